// Round 11
// baseline (3729.598 us; speedup 1.0000x reference)
//
#include <hip/hip_runtime.h>
#include <hip/hip_bf16.h>
#include <stdint.h>

#define HIDDEN 1024
#define FEAT   64
#define BATCH  512
#define SEQ    64
#define GATES  3072        // 3*HIDDEN

typedef __attribute__((ext_vector_type(4))) float f32x4;
typedef __attribute__((ext_vector_type(8))) short s16x8;   // 8 bf16 = 4 VGPRs (MFMA A/B frag)

#define MFMA16(a, b, c) __builtin_amdgcn_mfma_f32_16x16x32_bf16(a, b, c, 0, 0, 0)
#define VMCNT(n) asm volatile("s_waitcnt vmcnt(" #n ")" ::: "memory")
#define LGKMCNT0 asm volatile("s_waitcnt lgkmcnt(0)" ::: "memory")

__device__ inline unsigned short f2bf(float f) {
    unsigned u = __builtin_bit_cast(unsigned, f);
    u += 0x7fff + ((u >> 16) & 1);          // round-to-nearest-even
    return (unsigned short)(u >> 16);
}
__device__ inline float bf2f(unsigned short s) {
    unsigned u = ((unsigned)s) << 16;
    return __builtin_bit_cast(float, u);
}

#define GLOAD_LDS16(g, l) __builtin_amdgcn_global_load_lds( \
    (const __attribute__((address_space(1))) unsigned int*)(g), \
    (__attribute__((address_space(3))) unsigned int*)(l), 16, 0, 0)

// ---------------- weight/input conversion ----------------
// (3H, 1024) fp32 -> bf16, rows permuted so unit-tile ub's 48 rows {r:16,z:16,n:16} are contiguous
__global__ void k_conv_whh(const float* __restrict__ src, unsigned short* __restrict__ dst) {
    int i = blockIdx.x * 256 + threadIdx.x;          // 3072*1024 threads
    int d = i >> 10, k = i & 1023;
    int ub = d / 48, rem = d - ub * 48;
    int g = rem >> 4, jj = rem & 15;
    int srow = g * 1024 + ub * 16 + jj;
    dst[i] = f2bf(src[(size_t)srow * 1024 + k]);
}

// (3H, 64) fp32 -> bf16, same row permutation (layer-0 Wih)
__global__ void k_conv_wih0(const float* __restrict__ src, unsigned short* __restrict__ dst) {
    int i = blockIdx.x * 256 + threadIdx.x;          // 3072*64 threads
    int d = i >> 6, k = i & 63;
    int ub = d / 48, rem = d - ub * 48;
    int g = rem >> 4, jj = rem & 15;
    int srow = g * 1024 + ub * 16 + jj;
    dst[i] = f2bf(src[(size_t)srow * 64 + k]);
}

// x (B,T,F) fp32 -> xbf (T,B,F) bf16
__global__ void k_xpose(const float* __restrict__ x, unsigned short* __restrict__ xbf) {
    int i = blockIdx.x * blockDim.x + threadIdx.x;
    if (i >= BATCH * SEQ * FEAT) return;
    int f = i & 63, t = (i >> 6) & 63, b = i >> 12;
    xbf[((size_t)t * BATCH + b) * FEAT + f] = f2bf(x[i]);
}

// ---------------- chunk staging (round-7 verified addressing) ----------------
// LDS[row][col16] = src[row][col16 ^ (row&7)] (pre-swizzled source, linear dest — rule #21).
// W: 48 rows x 128 B = 6 groups (waves 0,1: 2 loads; waves 2,3: 1).
// A: 128 rows x 128 B = 16 groups (4 loads per wave).
// Per-wave issue count per chunk: wid<2 -> 6, else 5 (for counted vmcnt).
__device__ __forceinline__ void stage_pair(const char* ws, int wstr, const char* as, int astr,
                                           unsigned short* Wd, unsigned short* Ad,
                                           int wid, int lane)
{
    const int lrow = lane >> 3;
    const int lcol = lane & 7;
    for (int g = wid; g < 6; g += 4) {
        int row = g * 8 + lrow;
        int c16 = lcol ^ (row & 7);
        GLOAD_LDS16(ws + (size_t)row * wstr + c16 * 16, (char*)Wd + (g << 10));
    }
#pragma unroll
    for (int r = 0; r < 4; ++r) {
        int g = wid + r * 4;
        int row = g * 8 + lrow;
        int c16 = lcol ^ (row & 7);
        GLOAD_LDS16(as + (size_t)row * astr + c16 * 16, (char*)Ad + (g << 10));
    }
}

// ---------------- compute one 64-col K-chunk: 2 k-slices x 6 MFMA (round-7 verified) ----------------
template<int NSLOT>
__device__ __forceinline__ void compute_chunk(const unsigned short* aL, const unsigned short* wL,
                                              int wid, int lane, f32x4 (&acc)[2][4])
{
    const int l15 = lane & 15, hi = lane >> 4;
    const int swz = (l15 & 7) << 4;
    const char* ap = (const char*)aL;
    const char* wp = (const char*)wL;
#pragma unroll
    for (int ks = 0; ks < 2; ++ks) {
        const int kb = ks * 64 + (hi << 4);
        s16x8 a0 = *(const s16x8*)(ap + ((((wid * 32 + l15) * 128) + kb) ^ swz));
        s16x8 a1 = *(const s16x8*)(ap + ((((wid * 32 + 16 + l15) * 128) + kb) ^ swz));
        s16x8 b0 = *(const s16x8*)(wp + (((l15 * 128) + kb) ^ swz));
        s16x8 b1 = *(const s16x8*)(wp + ((((16 + l15) * 128) + kb) ^ swz));
        s16x8 b2 = *(const s16x8*)(wp + ((((32 + l15) * 128) + kb) ^ swz));
        acc[0][0]     = MFMA16(a0, b0, acc[0][0]);
        acc[0][1]     = MFMA16(a0, b1, acc[0][1]);
        acc[0][NSLOT] = MFMA16(a0, b2, acc[0][NSLOT]);
        acc[1][0]     = MFMA16(a1, b0, acc[1][0]);
        acc[1][1]     = MFMA16(a1, b1, acc[1][1]);
        acc[1][NSLOT] = MFMA16(a1, b2, acc[1][NSLOT]);
    }
}

// ---------------- wavefront stage kernel, v6: depth-3 pipeline ----------------
// Stage d: (L0,t=d), (L1,t=d-1), (L2,t=d-2). 768 blocks x 256 threads, 2 blocks/CU.
// Block: 128 batch rows x 16 units x 3 gates. K in 64-col chunks, TRIPLE-buffered LDS:
// iteration c stages chunk c+2 and computes chunk c, so each chunk's loads are waited
// ~2 iterations (~600-800 cy) after issue — matches L3 latency (round-10's depth-2 gave
// only ~300 cy cover; counted vmcnt alone changed nothing). In-flight = 2 chunks ->
// vmcnt(12)/(10) per wave class. acc slots: 0=r, 1=z, 2=xn, 3=hn.
__global__ __launch_bounds__(256, 2) void k_stage(
    int d,
    const unsigned short* __restrict__ xbf,
    unsigned short* __restrict__ h0,
    unsigned short* __restrict__ h1,
    unsigned short* __restrict__ h2,
    const unsigned short* __restrict__ wih0R,
    const unsigned short* __restrict__ whh0R,
    const unsigned short* __restrict__ wih1R,
    const unsigned short* __restrict__ whh1R,
    const unsigned short* __restrict__ wih2R,
    const unsigned short* __restrict__ whh2R,
    const float* __restrict__ bih0, const float* __restrict__ bhh0,
    const float* __restrict__ bih1, const float* __restrict__ bhh1,
    const float* __restrict__ bih2, const float* __restrict__ bhh2)
{
    __shared__ unsigned short Wb[3][48 * 64];    // 3 x 6 KB
    __shared__ unsigned short Ab[3][128 * 64];   // 3 x 16 KB
    const int bid = blockIdx.x;
    const int slot = bid & 7;
    const int p = (bid >> 3) % 24;
    const int bg = bid / 192;                    // batch group 0..3
    const int pair = slot + 8 * p;               // 0..191 (XCD-pinned: bg blocks share slot)
    const int layer = pair >> 6;
    const int ub = pair & 63;
    const int t = d - layer;
    if (t < 0 || t >= SEQ) return;

    const int tid = threadIdx.x;
    const int wid = tid >> 6, lane = tid & 63;
    const int l15 = lane & 15, hi = lane >> 4;
    const int brow0 = bg * 128;

    const unsigned short* inseq = (layer == 0) ? xbf : ((layer == 1) ? h0 : h1);
    unsigned short* outseq = (layer == 0) ? h0 : ((layer == 1) ? h1 : h2);
    const unsigned short* wihR = (layer == 0) ? wih0R : ((layer == 1) ? wih1R : wih2R);
    const unsigned short* whhR = (layer == 0) ? whh0R : ((layer == 1) ? whh1R : whh2R);

    const int astr1 = (layer == 0) ? 128 : 2048;
    const char* a1base = (layer == 0)
        ? (const char*)xbf + (size_t)t * BATCH * FEAT * 2 + (size_t)brow0 * 128
        : (const char*)inseq + (size_t)t * BATCH * HIDDEN * 2 + (size_t)brow0 * 2048;
    const char* w1base = (layer == 0)
        ? (const char*)wihR + (size_t)ub * 48 * 64 * 2
        : (const char*)wihR + (size_t)ub * 48 * 1024 * 2;
    const int wstr1 = (layer == 0) ? 128 : 2048;
    const char* a2base = (const char*)outseq + (size_t)(t - 1) * BATCH * HIDDEN * 2 + (size_t)brow0 * 2048;
    const char* w2base = (const char*)whhR + (size_t)ub * 48 * 1024 * 2;

    const int NCH1 = (layer == 0) ? 1 : 16;
    const int NCH2 = (t > 0) ? 16 : 0;
    const int total = NCH1 + NCH2;

    // per-chunk source resolver
    auto srcs = [&](int c, const char*& ws, int& wstr, const char*& as, int& astr) {
        if (c < NCH1) {
            ws = w1base + (size_t)c * 128; wstr = wstr1;
            as = a1base + (size_t)c * 128; astr = astr1;
        } else {
            int c2 = c - NCH1;
            ws = w2base + (size_t)c2 * 128; wstr = 2048;
            as = a2base + (size_t)c2 * 128; astr = 2048;
        }
    };
    auto stage_c = [&](int c, int buf) {
        const char* ws; int wstr; const char* as; int astr;
        srcs(c, ws, wstr, as, astr);
        stage_pair(ws, wstr, as, astr, Wb[buf], Ab[buf], wid, lane);
    };

    f32x4 acc[2][4];
    const f32x4 zero = {0.f, 0.f, 0.f, 0.f};
#pragma unroll
    for (int i = 0; i < 2; ++i)
#pragma unroll
        for (int s = 0; s < 4; ++s) acc[i][s] = zero;

    // prologue: stage chunks 0,1 into bufs 0,1
    stage_c(0, 0);
    if (1 < total) stage_c(1, 1);

    int cb = 0;                                  // buffer holding chunk c
    for (int c = 0; c < total; ++c) {
        int sb = cb + 2; if (sb >= 3) sb -= 3;   // buffer for chunk c+2
        if (c + 2 < total) {
            stage_c(c + 2, sb);
            if (wid < 2) VMCNT(12); else VMCNT(10);   // drain chunk c only; c+1,c+2 in flight
        } else if (c + 1 < total) {
            if (wid < 2) VMCNT(6); else VMCNT(5);     // drain chunk c; c+1 in flight
        } else {
            VMCNT(0);
        }
        __builtin_amdgcn_s_barrier();
        __builtin_amdgcn_sched_barrier(0);
        if (c < NCH1) compute_chunk<2>(Ab[cb], Wb[cb], wid, lane, acc);
        else          compute_chunk<3>(Ab[cb], Wb[cb], wid, lane, acc);
        LGKMCNT0;
        __builtin_amdgcn_sched_barrier(0);
        __builtin_amdgcn_s_barrier();
        ++cb; if (cb >= 3) cb -= 3;
    }

    // ---- fused gate epilogue: each wave writes its 32 rows ----
    const float* bih = (layer == 0) ? bih0 : ((layer == 1) ? bih1 : bih2);
    const float* bhh = (layer == 0) ? bhh0 : ((layer == 1) ? bhh1 : bhh2);
    const int j = ub * 16 + l15;
    const float br  = bih[j] + bhh[j];
    const float bz  = bih[HIDDEN + j] + bhh[HIDDEN + j];
    const float bxn = bih[2 * HIDDEN + j];
    const float bhn = bhh[2 * HIDDEN + j];
    const unsigned short* hprev = outseq + (size_t)((t > 0) ? (t - 1) : 0) * (BATCH * HIDDEN);
    unsigned short* hout = outseq + (size_t)t * (BATCH * HIDDEN);
#pragma unroll
    for (int i = 0; i < 2; ++i)
#pragma unroll
        for (int r = 0; r < 4; ++r) {
            int brow = brow0 + wid * 32 + i * 16 + hi * 4 + r;
            size_t hidx = (size_t)brow * HIDDEN + j;
            float rg = 1.f / (1.f + __expf(-(acc[i][0][r] + br)));
            float zg = 1.f / (1.f + __expf(-(acc[i][1][r] + bz)));
            float ng = tanhf(acc[i][2][r] + bxn + rg * (acc[i][3][r] + bhn));
            float hv = (t > 0) ? bf2f(hprev[hidx]) : 0.f;
            float hnew = (1.f - zg) * ng + zg * hv;
            hout[hidx] = f2bf(hnew);
        }
}

// ---------------- batch-norm over batch: coalesced two-phase, deterministic ----------------
__global__ void k_bn_part(const unsigned short* __restrict__ h, float* __restrict__ part) {
    int j = threadIdx.x;                 // 1024 threads = all units
    int blk = blockIdx.x;                // 16 blocks x 32 rows
    float s = 0.f, q = 0.f;
    for (int b = blk * 32; b < blk * 32 + 32; ++b) {
        float v = bf2f(h[(size_t)b * HIDDEN + j]);
        s += v; q += v * v;
    }
    part[blk * 2048 + j] = s;
    part[blk * 2048 + 1024 + j] = q;
}

__global__ void k_bn_fold(const float* __restrict__ part, const float* __restrict__ gamma,
                          const float* __restrict__ beta, float* __restrict__ a, float* __restrict__ bb)
{
    int j = blockIdx.x * 256 + threadIdx.x;   // HIDDEN threads
    float s = 0.f, q = 0.f;
    for (int p = 0; p < 16; ++p) {
        s += part[p * 2048 + j];
        q += part[p * 2048 + 1024 + j];
    }
    float mu = s * (1.f / BATCH);
    float var = q * (1.f / BATCH) - mu * mu;
    float rs = rsqrtf(var + 1e-5f);
    float aj = gamma[j] * rs;
    a[j] = aj;
    bb[j] = beta[j] - mu * aj;
}

// ---------------- FC(1024->1) + sigmoid ----------------
__global__ void k_fc(const unsigned short* __restrict__ h, const float* __restrict__ a, const float* __restrict__ bb,
                     const float* __restrict__ fcW, const float* __restrict__ fcb, float* __restrict__ out)
{
    int b = blockIdx.x;
    int lane = threadIdx.x;
    float s = 0.f;
    for (int j = lane; j < HIDDEN; j += 64)
        s += (bf2f(h[(size_t)b * HIDDEN + j]) * a[j] + bb[j]) * fcW[j];
#pragma unroll
    for (int m = 32; m; m >>= 1) s += __shfl_xor(s, m, 64);
    if (lane == 0) out[b] = 1.f / (1.f + __expf(-(s + fcb[0])));
}

// ---------------- driver ----------------
extern "C" void kernel_launch(void* const* d_in, const int* in_sizes, int n_in,
                              void* d_out, int out_size, void* d_ws, size_t ws_size,
                              hipStream_t stream)
{
    const float* x = (const float*)d_in[0];
    const float* W_ih[3] = {(const float*)d_in[1], (const float*)d_in[5], (const float*)d_in[9]};
    const float* W_hh[3] = {(const float*)d_in[2], (const float*)d_in[6], (const float*)d_in[10]};
    const float* b_ih[3] = {(const float*)d_in[3], (const float*)d_in[7], (const float*)d_in[11]};
    const float* b_hh[3] = {(const float*)d_in[4], (const float*)d_in[8], (const float*)d_in[12]};
    const float* gamma = (const float*)d_in[13];
    const float* beta  = (const float*)d_in[14];
    const float* fcW   = (const float*)d_in[15];
    const float* fcb   = (const float*)d_in[16];

    char* ws = (char*)d_ws;
    size_t off = 0;
    auto alloc = [&](size_t bytes) -> void* {
        void* p = ws + off;
        off = (off + bytes + 255) & ~(size_t)255;
        return p;
    };
    unsigned short* wih0R = (unsigned short*)alloc((size_t)GATES * FEAT * 2);
    unsigned short* whh0R = (unsigned short*)alloc((size_t)GATES * HIDDEN * 2);
    unsigned short* wih1R = (unsigned short*)alloc((size_t)GATES * HIDDEN * 2);
    unsigned short* whh1R = (unsigned short*)alloc((size_t)GATES * HIDDEN * 2);
    unsigned short* wih2R = (unsigned short*)alloc((size_t)GATES * HIDDEN * 2);
    unsigned short* whh2R = (unsigned short*)alloc((size_t)GATES * HIDDEN * 2);
    unsigned short* xbf = (unsigned short*)alloc((size_t)SEQ * BATCH * FEAT * 2);
    unsigned short* h0  = (unsigned short*)alloc((size_t)SEQ * BATCH * HIDDEN * 2);
    unsigned short* h1  = (unsigned short*)alloc((size_t)SEQ * BATCH * HIDDEN * 2);
    unsigned short* h2  = (unsigned short*)alloc((size_t)SEQ * BATCH * HIDDEN * 2);
    float* part = (float*)alloc(16 * 2048 * 4);
    float* abuf = (float*)alloc(HIDDEN * 4);
    float* bbuf = (float*)alloc(HIDDEN * 4);

    // weights -> bf16, permuted (stateless every call)
    k_conv_wih0<<<(GATES * FEAT) / 256, 256, 0, stream>>>(W_ih[0], wih0R);
    k_conv_whh<<<(GATES * HIDDEN) / 256, 256, 0, stream>>>(W_hh[0], whh0R);
    k_conv_whh<<<(GATES * HIDDEN) / 256, 256, 0, stream>>>(W_ih[1], wih1R);
    k_conv_whh<<<(GATES * HIDDEN) / 256, 256, 0, stream>>>(W_hh[1], whh1R);
    k_conv_whh<<<(GATES * HIDDEN) / 256, 256, 0, stream>>>(W_ih[2], wih2R);
    k_conv_whh<<<(GATES * HIDDEN) / 256, 256, 0, stream>>>(W_hh[2], whh2R);
    k_xpose<<<(BATCH * SEQ * FEAT + 255) / 256, 256, 0, stream>>>(x, xbf);

    // wavefront over (layer, t): 66 stages
    for (int d = 0; d < SEQ + 2; ++d)
        k_stage<<<768, 256, 0, stream>>>(d, xbf, h0, h1, h2,
                                         wih0R, whh0R, wih1R, whh1R, wih2R, whh2R,
                                         b_ih[0], b_hh[0], b_ih[1], b_hh[1], b_ih[2], b_hh[2]);

    const unsigned short* hlast = h2 + (size_t)(SEQ - 1) * (BATCH * HIDDEN);
    k_bn_part<<<16, 1024, 0, stream>>>(hlast, part);
    k_bn_fold<<<HIDDEN / 256, 256, 0, stream>>>(part, gamma, beta, abuf, bbuf);
    k_fc<<<BATCH, 64, 0, stream>>>(hlast, abuf, bbuf, fcW, fcb, (float*)d_out);
}

// Round 13
// 2204.094 us; speedup vs baseline: 1.6921x; 1.6921x over previous
//
#include <hip/hip_runtime.h>
#include <hip/hip_bf16.h>
#include <stdint.h>

#define HIDDEN 1024
#define FEAT   64
#define BATCH  512
#define SEQ    64
#define GATES  3072        // 3*HIDDEN

typedef __attribute__((ext_vector_type(4))) float f32x4;
typedef __attribute__((ext_vector_type(8))) short s16x8;   // 8 bf16 = 4 VGPRs (MFMA A/B frag)

#define MFMA16(a, b, c) __builtin_amdgcn_mfma_f32_16x16x32_bf16(a, b, c, 0, 0, 0)
#define VMCNT(n) asm volatile("s_waitcnt vmcnt(" #n ")" ::: "memory")
#define LGKMCNT0 asm volatile("s_waitcnt lgkmcnt(0)" ::: "memory")

__device__ inline unsigned short f2bf(float f) {
    unsigned u = __builtin_bit_cast(unsigned, f);
    u += 0x7fff + ((u >> 16) & 1);          // round-to-nearest-even
    return (unsigned short)(u >> 16);
}
__device__ inline float bf2f(unsigned short s) {
    unsigned u = ((unsigned)s) << 16;
    return __builtin_bit_cast(float, u);
}

#define GLOAD_LDS16(g, l) __builtin_amdgcn_global_load_lds( \
    (const __attribute__((address_space(1))) unsigned int*)(g), \
    (__attribute__((address_space(3))) unsigned int*)(l), 16, 0, 0)

// ---------------- weight conversion: chunk-tiled, PLAIN content ----------------
// dst layout: [ub][c][srow][scol], 48x64 bf16 per (ub,c) contiguous (6 KB).
// dst[ub][c][srow][scol] = W[g*1024+ub*16+jj][c*64+scol], g=srow>>4, jj=srow&15.
// NO pre-swizzle here: stage_pair applies the single XOR (round-12 bug: both sides
// swizzled -> cancellation -> linear LDS read as swizzled. Swizzle exactly once.)
__global__ void k_conv_whh_t(const float* __restrict__ src, unsigned short* __restrict__ dst) {
    int i = blockIdx.x * 256 + threadIdx.x;          // 3072*1024 threads
    int ub = i / 49152;                              // 16 chunks * 3072
    int r  = i - ub * 49152;
    int c  = r / 3072;
    int r2 = r - c * 3072;
    int srow = r2 >> 6, scol = r2 & 63;
    int src_row = ((srow >> 4) << 10) + (ub << 4) + (srow & 15);
    dst[i] = f2bf(src[(size_t)src_row * 1024 + (c << 6) + scol]);
}

// layer-0 Wih: [ub][48][64], 6 KB per ub, same row permutation, plain content
__global__ void k_conv_wih0_t(const float* __restrict__ src, unsigned short* __restrict__ dst) {
    int i = blockIdx.x * 256 + threadIdx.x;          // 3072*64 threads
    int ub = i / 3072;
    int r  = i - ub * 3072;
    int srow = r >> 6, scol = r & 63;
    int src_row = ((srow >> 4) << 10) + (ub << 4) + (srow & 15);
    dst[i] = f2bf(src[(size_t)src_row * 64 + scol]);
}

// x (B,T,F) fp32 -> xbf (T,B,F) bf16  (already chunk-contiguous: 64-col rows)
__global__ void k_xpose(const float* __restrict__ x, unsigned short* __restrict__ xbf) {
    int i = blockIdx.x * blockDim.x + threadIdx.x;
    if (i >= BATCH * SEQ * FEAT) return;
    int f = i & 63, t = (i >> 6) & 63, b = i >> 12;
    xbf[((size_t)t * BATCH + b) * FEAT + f] = f2bf(x[i]);
}

// ---------------- chunk staging: fully contiguous sources, swizzle applied ONCE ----------------
// W chunk: 6 KB contiguous; A chunk: 16 KB contiguous. Each wave instr covers a dense 1 KB
// (lane-permuted within the group — coalescing unchanged). LDS[row][s16] = src[row][s16^(row&7)];
// read side XORs ((row&7)<<4) — rule #21, round-7-verified 0 conflicts.
__device__ __forceinline__ void stage_pair(const char* ws, const char* as,
                                           unsigned short* Wd, unsigned short* Ad,
                                           int wid, int lane)
{
    const int lrow = lane >> 3;
    const int srcoff = lrow * 128 + (((lane & 7) ^ (lrow & 7)) << 4);
    for (int g = wid; g < 6; g += 4)
        GLOAD_LDS16(ws + (g << 10) + srcoff, (char*)Wd + (g << 10));
#pragma unroll
    for (int r = 0; r < 4; ++r) {
        int g = wid + r * 4;
        GLOAD_LDS16(as + (g << 10) + srcoff, (char*)Ad + (g << 10));
    }
}

// ---------------- compute one 64-col K-chunk: 2 k-slices x 6 MFMA (verified) ----------------
template<int NSLOT>
__device__ __forceinline__ void compute_chunk(const unsigned short* aL, const unsigned short* wL,
                                              int wid, int lane, f32x4 (&acc)[2][4])
{
    const int l15 = lane & 15, hi = lane >> 4;
    const int swz = (l15 & 7) << 4;
    const char* ap = (const char*)aL;
    const char* wp = (const char*)wL;
#pragma unroll
    for (int ks = 0; ks < 2; ++ks) {
        const int kb = ks * 64 + (hi << 4);
        s16x8 a0 = *(const s16x8*)(ap + ((((wid * 32 + l15) * 128) + kb) ^ swz));
        s16x8 a1 = *(const s16x8*)(ap + ((((wid * 32 + 16 + l15) * 128) + kb) ^ swz));
        s16x8 b0 = *(const s16x8*)(wp + (((l15 * 128) + kb) ^ swz));
        s16x8 b1 = *(const s16x8*)(wp + ((((16 + l15) * 128) + kb) ^ swz));
        s16x8 b2 = *(const s16x8*)(wp + ((((32 + l15) * 128) + kb) ^ swz));
        acc[0][0]     = MFMA16(a0, b0, acc[0][0]);
        acc[0][1]     = MFMA16(a0, b1, acc[0][1]);
        acc[0][NSLOT] = MFMA16(a0, b2, acc[0][NSLOT]);
        acc[1][0]     = MFMA16(a1, b0, acc[1][0]);
        acc[1][1]     = MFMA16(a1, b1, acc[1][1]);
        acc[1][NSLOT] = MFMA16(a1, b2, acc[1][NSLOT]);
    }
}

// ---------------- wavefront stage kernel, v7b: contiguous chunks, depth-2, 3 blocks/CU ----------------
// Stage d: (L0,t=d), (L1,t=d-1), (L2,t=d-2). 768 blocks x 256 threads = exactly 3/CU.
// h layout: [t][kchunk(16)][512][64] bf16 — A chunks contiguous 16 KB.
// W layout: [ub][chunk][48x64] — W chunks contiguous 6 KB. acc: 0=r, 1=z, 2=xn, 3=hn.
__global__ __launch_bounds__(256, 3) void k_stage(
    int d,
    const unsigned short* __restrict__ xbf,
    unsigned short* __restrict__ h0,
    unsigned short* __restrict__ h1,
    unsigned short* __restrict__ h2,
    const unsigned short* __restrict__ wih0R,
    const unsigned short* __restrict__ whh0R,
    const unsigned short* __restrict__ wih1R,
    const unsigned short* __restrict__ whh1R,
    const unsigned short* __restrict__ wih2R,
    const unsigned short* __restrict__ whh2R,
    const float* __restrict__ bih0, const float* __restrict__ bhh0,
    const float* __restrict__ bih1, const float* __restrict__ bhh1,
    const float* __restrict__ bih2, const float* __restrict__ bhh2)
{
    __shared__ unsigned short Wb[2][48 * 64];    // 2 x 6 KB
    __shared__ unsigned short Ab[2][128 * 64];   // 2 x 16 KB
    const int bid = blockIdx.x;
    const int slot = bid & 7;
    const int p = (bid >> 3) % 24;
    const int bg = bid / 192;                    // batch group 0..3
    const int pair = slot + 8 * p;               // 0..191 (XCD-pinned: bg blocks share slot)
    const int layer = pair >> 6;
    const int ub = pair & 63;
    const int t = d - layer;
    if (t < 0 || t >= SEQ) return;

    const int tid = threadIdx.x;
    const int wid = tid >> 6, lane = tid & 63;
    const int l15 = lane & 15, hi = lane >> 4;
    const int brow0 = bg * 128;

    const unsigned short* inseq = (layer == 0) ? xbf : ((layer == 1) ? h0 : h1);
    unsigned short* outseq = (layer == 0) ? h0 : ((layer == 1) ? h1 : h2);
    const unsigned short* wihR = (layer == 0) ? wih0R : ((layer == 1) ? wih1R : wih2R);
    const unsigned short* whhR = (layer == 0) ? whh0R : ((layer == 1) ? whh1R : whh2R);

    // byte bases (chunk advances: W 6144, A 65536)
    const char* a1base = (layer == 0)
        ? (const char*)xbf + (size_t)t * 65536 + (size_t)brow0 * 128
        : (const char*)inseq + (size_t)t * 1048576 + (size_t)brow0 * 128;
    const char* w1base = (layer == 0)
        ? (const char*)wih0R + (size_t)ub * 6144
        : (const char*)wihR + (size_t)ub * 98304;
    const char* a2base = (const char*)outseq + (size_t)(t - 1) * 1048576 + (size_t)brow0 * 128;
    const char* w2base = (const char*)whhR + (size_t)ub * 98304;

    const int NCH1 = (layer == 0) ? 1 : 16;
    const int NCH2 = (t > 0) ? 16 : 0;
    const int total = NCH1 + NCH2;

    auto srcs = [&](int c, const char*& ws, const char*& as) {
        if (c < NCH1) {
            ws = w1base + (size_t)c * 6144;
            as = a1base + (size_t)c * 65536;
        } else {
            int c2 = c - NCH1;
            ws = w2base + (size_t)c2 * 6144;
            as = a2base + (size_t)c2 * 65536;
        }
    };

    f32x4 acc[2][4];
    const f32x4 zero = {0.f, 0.f, 0.f, 0.f};
#pragma unroll
    for (int i = 0; i < 2; ++i)
#pragma unroll
        for (int s = 0; s < 4; ++s) acc[i][s] = zero;

    // prologue: stage chunk 0 into buf 0
    {
        const char* ws; const char* as;
        srcs(0, ws, as);
        stage_pair(ws, as, Wb[0], Ab[0], wid, lane);
    }

    for (int c = 0; c < total; ++c) {
        const int cb = c & 1;
        if (c + 1 < total) {
            const char* ws; const char* as;
            srcs(c + 1, ws, as);
            stage_pair(ws, as, Wb[cb ^ 1], Ab[cb ^ 1], wid, lane);
            // wait chunk-c loads only; chunk-(c+1) stays in flight (T4)
            if (wid < 2) VMCNT(6); else VMCNT(5);
        } else {
            VMCNT(0);
        }
        __builtin_amdgcn_s_barrier();
        __builtin_amdgcn_sched_barrier(0);
        if (c < NCH1) compute_chunk<2>(Ab[cb], Wb[cb], wid, lane, acc);
        else          compute_chunk<3>(Ab[cb], Wb[cb], wid, lane, acc);
        LGKMCNT0;
        __builtin_amdgcn_sched_barrier(0);
        __builtin_amdgcn_s_barrier();
    }

    // ---- fused gate epilogue: each wave writes its 32 rows ----
    const float* bih = (layer == 0) ? bih0 : ((layer == 1) ? bih1 : bih2);
    const float* bhh = (layer == 0) ? bhh0 : ((layer == 1) ? bhh1 : bhh2);
    const int j = ub * 16 + l15;
    const float br  = bih[j] + bhh[j];
    const float bz  = bih[HIDDEN + j] + bhh[HIDDEN + j];
    const float bxn = bih[2 * HIDDEN + j];
    const float bhn = bhh[2 * HIDDEN + j];
    const unsigned short* hprev = outseq + (size_t)((t > 0) ? (t - 1) : 0) * (16 * 512 * 64);
    unsigned short* hout = outseq + (size_t)t * (16 * 512 * 64);
    const int jc = (ub >> 2);                 // chunk of unit j
    const int jcol = (ub & 3) * 16 + l15;     // col within chunk
#pragma unroll
    for (int i = 0; i < 2; ++i)
#pragma unroll
        for (int r = 0; r < 4; ++r) {
            int brow = brow0 + wid * 32 + i * 16 + hi * 4 + r;
            size_t hidx = (size_t)(jc * 512 + brow) * 64 + jcol;
            float rg = 1.f / (1.f + __expf(-(acc[i][0][r] + br)));
            float zg = 1.f / (1.f + __expf(-(acc[i][1][r] + bz)));
            float ng = tanhf(acc[i][2][r] + bxn + rg * (acc[i][3][r] + bhn));
            float hv = (t > 0) ? bf2f(hprev[hidx]) : 0.f;
            float hnew = (1.f - zg) * ng + zg * hv;
            hout[hidx] = f2bf(hnew);
        }
}

// ---------------- batch-norm over batch (tiled h layout), deterministic ----------------
__global__ void k_bn_part(const unsigned short* __restrict__ h, float* __restrict__ part) {
    int j = threadIdx.x;                 // 1024 threads = all units
    int blk = blockIdx.x;                // 16 blocks x 32 rows
    const int jc = j >> 6, jcol = j & 63;
    float s = 0.f, q = 0.f;
    for (int b = blk * 32; b < blk * 32 + 32; ++b) {
        float v = bf2f(h[(size_t)(jc * 512 + b) * 64 + jcol]);
        s += v; q += v * v;
    }
    part[blk * 2048 + j] = s;
    part[blk * 2048 + 1024 + j] = q;
}

__global__ void k_bn_fold(const float* __restrict__ part, const float* __restrict__ gamma,
                          const float* __restrict__ beta, float* __restrict__ a, float* __restrict__ bb)
{
    int j = blockIdx.x * 256 + threadIdx.x;   // HIDDEN threads
    float s = 0.f, q = 0.f;
    for (int p = 0; p < 16; ++p) {
        s += part[p * 2048 + j];
        q += part[p * 2048 + 1024 + j];
    }
    float mu = s * (1.f / BATCH);
    float var = q * (1.f / BATCH) - mu * mu;
    float rs = rsqrtf(var + 1e-5f);
    float aj = gamma[j] * rs;
    a[j] = aj;
    bb[j] = beta[j] - mu * aj;
}

// ---------------- FC(1024->1) + sigmoid (tiled h layout) ----------------
__global__ void k_fc(const unsigned short* __restrict__ h, const float* __restrict__ a, const float* __restrict__ bb,
                     const float* __restrict__ fcW, const float* __restrict__ fcb, float* __restrict__ out)
{
    int b = blockIdx.x;
    int lane = threadIdx.x;
    float s = 0.f;
    for (int j = lane; j < HIDDEN; j += 64)
        s += (bf2f(h[(size_t)((j >> 6) * 512 + b) * 64 + (j & 63)]) * a[j] + bb[j]) * fcW[j];
#pragma unroll
    for (int m = 32; m; m >>= 1) s += __shfl_xor(s, m, 64);
    if (lane == 0) out[b] = 1.f / (1.f + __expf(-(s + fcb[0])));
}

// ---------------- driver ----------------
extern "C" void kernel_launch(void* const* d_in, const int* in_sizes, int n_in,
                              void* d_out, int out_size, void* d_ws, size_t ws_size,
                              hipStream_t stream)
{
    const float* x = (const float*)d_in[0];
    const float* W_ih[3] = {(const float*)d_in[1], (const float*)d_in[5], (const float*)d_in[9]};
    const float* W_hh[3] = {(const float*)d_in[2], (const float*)d_in[6], (const float*)d_in[10]};
    const float* b_ih[3] = {(const float*)d_in[3], (const float*)d_in[7], (const float*)d_in[11]};
    const float* b_hh[3] = {(const float*)d_in[4], (const float*)d_in[8], (const float*)d_in[12]};
    const float* gamma = (const float*)d_in[13];
    const float* beta  = (const float*)d_in[14];
    const float* fcW   = (const float*)d_in[15];
    const float* fcb   = (const float*)d_in[16];

    char* ws = (char*)d_ws;
    size_t off = 0;
    auto alloc = [&](size_t bytes) -> void* {
        void* p = ws + off;
        off = (off + bytes + 255) & ~(size_t)255;
        return p;
    };
    unsigned short* wih0R = (unsigned short*)alloc((size_t)GATES * FEAT * 2);
    unsigned short* whh0R = (unsigned short*)alloc((size_t)GATES * HIDDEN * 2);
    unsigned short* wih1R = (unsigned short*)alloc((size_t)GATES * HIDDEN * 2);
    unsigned short* whh1R = (unsigned short*)alloc((size_t)GATES * HIDDEN * 2);
    unsigned short* wih2R = (unsigned short*)alloc((size_t)GATES * HIDDEN * 2);
    unsigned short* whh2R = (unsigned short*)alloc((size_t)GATES * HIDDEN * 2);
    unsigned short* xbf = (unsigned short*)alloc((size_t)SEQ * BATCH * FEAT * 2);
    unsigned short* h0  = (unsigned short*)alloc((size_t)SEQ * BATCH * HIDDEN * 2);
    unsigned short* h1  = (unsigned short*)alloc((size_t)SEQ * BATCH * HIDDEN * 2);
    unsigned short* h2  = (unsigned short*)alloc((size_t)SEQ * BATCH * HIDDEN * 2);
    float* part = (float*)alloc(16 * 2048 * 4);
    float* abuf = (float*)alloc(HIDDEN * 4);
    float* bbuf = (float*)alloc(HIDDEN * 4);

    // weights -> bf16, chunk-tiled + gate-permuted (plain content; stateless every call)
    k_conv_wih0_t<<<(GATES * FEAT) / 256, 256, 0, stream>>>(W_ih[0], wih0R);
    k_conv_whh_t<<<(GATES * HIDDEN) / 256, 256, 0, stream>>>(W_hh[0], whh0R);
    k_conv_whh_t<<<(GATES * HIDDEN) / 256, 256, 0, stream>>>(W_ih[1], wih1R);
    k_conv_whh_t<<<(GATES * HIDDEN) / 256, 256, 0, stream>>>(W_hh[1], whh1R);
    k_conv_whh_t<<<(GATES * HIDDEN) / 256, 256, 0, stream>>>(W_ih[2], wih2R);
    k_conv_whh_t<<<(GATES * HIDDEN) / 256, 256, 0, stream>>>(W_hh[2], whh2R);
    k_xpose<<<(BATCH * SEQ * FEAT + 255) / 256, 256, 0, stream>>>(x, xbf);

    // wavefront over (layer, t): 66 stages
    for (int d = 0; d < SEQ + 2; ++d)
        k_stage<<<768, 256, 0, stream>>>(d, xbf, h0, h1, h2,
                                         wih0R, whh0R, wih1R, whh1R, wih2R, whh2R,
                                         b_ih[0], b_hh[0], b_ih[1], b_hh[1], b_ih[2], b_hh[2]);

    const unsigned short* hlast = h2 + (size_t)(SEQ - 1) * (BATCH * HIDDEN);
    k_bn_part<<<16, 1024, 0, stream>>>(hlast, part);
    k_bn_fold<<<HIDDEN / 256, 256, 0, stream>>>(part, gamma, beta, abuf, bbuf);
    k_fc<<<BATCH, 64, 0, stream>>>(hlast, abuf, bbuf, fcW, fcb, (float*)d_out);
}